// Round 2
// baseline (75052.411 us; speedup 1.0000x reference)
//
#include <hip/hip_runtime.h>
#include <stdint.h>
#include <math.h>

#define TT   512      // sequence length / decode steps
#define HH_  1024     // hidden
#define VV   32000    // vocab
#define NB   256      // persistent blocks (1 per CU)
#define BT   512      // threads per block (8 waves)

// control region (bytes): [0..4) gen, [8..24) slot u64[2], [1024 + blk*64) flags
#define CTRL_BYTES 17408
// ws layout (float offsets)
#define OF_XS0 4352
#define OF_XS1 (OF_XS0 + TT*HH_)
#define OF_EH  (OF_XS1 + TT*HH_)        // enc h ping-pong [2 par][2 dir][512]
#define OF_HHF (OF_EH + 2048)           // enc final h [2 layer][1024]
#define OF_CCF (OF_HHF + 2048)
#define OF_DH  (OF_CCF + 2048)          // dec h [2 layer][2 par][1024]
#define OF_LOG (OF_DH + 4096)           // logits [512][32000]

__device__ __forceinline__ float wredsum(float v){
#pragma unroll
  for (int s = 32; s > 0; s >>= 1) v += __shfl_xor(v, s, 64);
  return v;
}
__device__ __forceinline__ float sigm(float x){ return 1.f/(1.f + __expf(-x)); }
__device__ __forceinline__ float tanh_(float x){
  float e = __expf(-2.f*fabsf(x));
  float t = (1.f - e)/(1.f + e);
  return copysignf(t, x);
}
__device__ __forceinline__ unsigned long long packmax(float v, int idx){
  unsigned u = __float_as_uint(v);
  u = (u & 0x80000000u) ? ~u : (u | 0x80000000u);
  return ((unsigned long long)u << 32) | (unsigned)(~idx);
}

// distributed-flag grid barrier: per-block flag cacheline, block0 aggregates.
__device__ __forceinline__ void gridbar(int* gen, int* flags, int g){
  __syncthreads();
  if (blockIdx.x == 0) {
    const int t = threadIdx.x;
    if (t >= 1 && t < NB) {
      while (__hip_atomic_load(&flags[t*16], __ATOMIC_ACQUIRE, __HIP_MEMORY_SCOPE_AGENT) < g)
        __builtin_amdgcn_s_sleep(1);
    }
    __syncthreads();
    if (t == 0)
      __hip_atomic_store(gen, g, __ATOMIC_RELEASE, __HIP_MEMORY_SCOPE_AGENT);
  } else {
    if (threadIdx.x == 0) {
      __hip_atomic_store(&flags[blockIdx.x*16], g, __ATOMIC_RELEASE, __HIP_MEMORY_SCOPE_AGENT);
      while (__hip_atomic_load(gen, __ATOMIC_ACQUIRE, __HIP_MEMORY_SCOPE_AGENT) < g)
        __builtin_amdgcn_s_sleep(4);
    }
    __syncthreads();
  }
}

__global__ __launch_bounds__(BT, 1) void seq2seq_k(
    const int*   __restrict__ x,
    const float* __restrict__ enc_emb,
    const float* __restrict__ enc_Wih,   // [2][2][2048][1024]
    const float* __restrict__ enc_Whh,   // [2][2][2048][512]
    const float* __restrict__ enc_b,     // [2][2][2048]
    const float* __restrict__ dec_emb,
    const float* __restrict__ dec_Wih,   // [2][4096][1024]
    const float* __restrict__ dec_Whh,   // [2][4096][1024]
    const float* __restrict__ dec_b,     // [2][4096]
    const float* __restrict__ clf_W,     // [32000][1024]
    const float* __restrict__ clf_b,     // [32000]
    float* __restrict__ ws)
{
  const int blk = blockIdx.x, tid = threadIdx.x;
  const int wave = tid >> 6, lane = tid & 63;
  int* genp = (int*)ws;
  unsigned long long* slots = (unsigned long long*)((char*)ws + 8);
  int* flags = (int*)((char*)ws + 1024);
  float* xs0 = ws + OF_XS0;
  float* xs1 = ws + OF_XS1;
  float* EH  = ws + OF_EH;
  float* HHf = ws + OF_HHF;
  float* CCf = ws + OF_CCF;
  float* DH  = ws + OF_DH;
  float* LG  = ws + OF_LOG;

  __shared__ float lds[32768];          // 128 KiB: enc layer slice (98KB) / dec L0 slice (128KB)
  __shared__ float sg[4][2][4];
  __shared__ float cbv[8];
  __shared__ int   cbi[8];
  __shared__ int   stok;

  int bgen = 0;
#define GB() do { ++bgen; gridbar(genp, flags, bgen); } while(0)

  // ---- prologue: embed encoder input (float4), zero EH ----
  {
    const float4* emb4 = (const float4*)enc_emb;
    float4* xs04 = (float4*)xs0;
    for (int i4 = blk*BT + tid; i4 < TT*256; i4 += NB*BT) {
      int t = i4 >> 8, d4 = i4 & 255;
      xs04[i4] = emb4[(size_t)x[t]*256 + d4];
    }
    for (int i = blk*BT + tid; i < 2048; i += NB*BT) EH[i] = 0.f;
  }
  GB();

  // ---- encoder: 2 layers, fwd+bwd concurrent, weights LDS-resident ----
  const float* xsrc = xs0;
#pragma unroll 1
  for (int l = 0; l < 2; ++l) {
    const float* Wih = enc_Wih + (size_t)l*2*2048*1024;
    const float* Whh = enc_Whh + (size_t)l*2*2048*512;
    __syncthreads();
    // load this block's weight slice: [4 pl][4 gate][1024 Wih | 512 Whh]
#pragma unroll 1
    for (int pl = 0; pl < 4; ++pl) {
      const int p = blk*4 + pl, dir = p >> 9, j = p & 511;
      const float* wbase = Wih + (size_t)dir*2048*1024;
      const float* hbase = Whh + (size_t)dir*2048*512;
#pragma unroll 1
      for (int g = 0; g < 4; ++g) {
        float* dst = lds + pl*6144 + g*1536;
        const float* s1 = wbase + (size_t)(g*512 + j)*1024;
        for (int k = tid; k < 1024; k += BT) dst[k] = s1[k];
        const float* s2 = hbase + (size_t)(g*512 + j)*512;
        for (int k = tid; k < 512; k += BT) dst[1024 + k] = s2[k];
      }
    }
    const int pe = blk*4 + (tid & 3), dire = pe >> 9, je = pe & 511;
    const float* Bb = enc_b + l*2*2048 + dire*2048;
    float bi_ = Bb[je], bf_ = Bb[512 + je], bg_ = Bb[1024 + je], bo_ = Bb[1536 + je];
    float creg = 0.f;
    __syncthreads();

#pragma unroll 1
    for (int s = 0; s < TT; ++s) {
      const int par = s & 1;
      {
        const int pl = wave >> 1, half = wave & 1;
        const int p = blk*4 + pl, dir = p >> 9;
        const int t = dir ? (TT-1-s) : s;
        const float4* xr4 = (const float4*)(xsrc + (size_t)t*HH_);
        const float4* h4  = (const float4*)(EH + par*1024 + dir*512);
        float4 xv0 = xr4[half*128 + lane];
        float4 xv1 = xr4[half*128 + 64 + lane];
        float4 hv  = h4[half*64 + lane];
        const float* wl = lds + pl*6144;
        float acc[4];
#pragma unroll
        for (int g = 0; g < 4; ++g) {
          const float4* wv = (const float4*)(wl + g*1536);
          const float4* wh = (const float4*)(wl + g*1536 + 1024);
          float4 wa = wv[half*128 + lane];
          float4 wb = wv[half*128 + 64 + lane];
          float4 wc = wh[half*64 + lane];
          acc[g] = wa.x*xv0.x + wa.y*xv0.y + wa.z*xv0.z + wa.w*xv0.w
                 + wb.x*xv1.x + wb.y*xv1.y + wb.z*xv1.z + wb.w*xv1.w
                 + wc.x*hv.x  + wc.y*hv.y  + wc.z*hv.z  + wc.w*hv.w;
        }
#pragma unroll
        for (int g = 0; g < 4; ++g) acc[g] = wredsum(acc[g]);
        if (lane == 0) { sg[pl][half][0]=acc[0]; sg[pl][half][1]=acc[1]; sg[pl][half][2]=acc[2]; sg[pl][half][3]=acc[3]; }
      }
      __syncthreads();
      if (tid < 4) {
        float gi = sg[tid][0][0]+sg[tid][1][0] + bi_;
        float gf = sg[tid][0][1]+sg[tid][1][1] + bf_;
        float gg = sg[tid][0][2]+sg[tid][1][2] + bg_;
        float go = sg[tid][0][3]+sg[tid][1][3] + bo_;
        float cn = sigm(gf)*creg + sigm(gi)*tanh_(gg);
        float hn = sigm(go)*tanh_(cn);
        creg = cn;
        const int te = dire ? (TT-1-s) : s;
        EH[(par^1)*1024 + dire*512 + je] = hn;
        if (l == 0) xs1[(size_t)te*HH_ + dire*512 + je] = hn;
        if (s == TT-1) { HHf[l*1024 + dire*512 + je] = hn; CCf[l*1024 + dire*512 + je] = cn; }
      }
      GB();
    }
    if (l == 0) {
      for (int i = blk*BT + tid; i < 2048; i += NB*BT) EH[i] = 0.f;
      xsrc = xs1;
      GB();
    }
  }

  // ---- decoder init: DH from enc finals, L0 weights -> LDS, biases/c in regs ----
  for (int i = blk*BT + tid; i < 2048; i += NB*BT) {
    int l2 = i >> 10, d = i & 1023;
    DH[(l2*2 + 0)*1024 + d] = HHf[i];
    DH[(l2*2 + 1)*1024 + d] = 0.f;
  }
  if (blk == 0 && tid == 0) {
    __hip_atomic_store(&slots[0], 0ull, __ATOMIC_RELAXED, __HIP_MEMORY_SCOPE_AGENT);
    __hip_atomic_store(&slots[1], 0ull, __ATOMIC_RELAXED, __HIP_MEMORY_SCOPE_AGENT);
  }
  __syncthreads();
#pragma unroll 1
  for (int pl = 0; pl < 4; ++pl) {
    const int j = blk*4 + pl;
#pragma unroll 1
    for (int g = 0; g < 4; ++g) {
      float* dst = lds + pl*8192 + g*2048;
      const float* s1 = dec_Wih + (size_t)(g*1024 + j)*1024;
      for (int k = tid; k < 1024; k += BT) dst[k] = s1[k];
      const float* s2 = dec_Whh + (size_t)(g*1024 + j)*1024;
      for (int k = tid; k < 1024; k += BT) dst[1024 + k] = s2[k];
    }
  }
  const int j2 = blk*4 + (tid & 3);
  const float b0i = dec_b[j2],        b0f = dec_b[1024 + j2],        b0g = dec_b[2048 + j2],        b0o = dec_b[3072 + j2];
  const float b1i = dec_b[4096 + j2], b1f = dec_b[4096 + 1024 + j2], b1g = dec_b[4096 + 2048 + j2], b1o = dec_b[4096 + 3072 + j2];
  float c0reg = CCf[j2], c1reg = CCf[1024 + j2];
  GB();

  // ---- decoder: 512 steps x {L0 (LDS) | L1 (stream) | clf+argmax} ----
#pragma unroll 1
  for (int t = 0; t < TT; ++t) {
    const int par = t & 1;
    if (tid == 0) {
      int tk = 1;
      if (t > 0) {
        unsigned long long pk = __hip_atomic_load(&slots[(t-1)&1], __ATOMIC_RELAXED, __HIP_MEMORY_SCOPE_AGENT);
        tk = (int)(~(unsigned)(pk & 0xFFFFFFFFull));
      }
      stok = tk;
    }
    __syncthreads();
    const int tok = stok;
    const int pl = wave >> 1, half = wave & 1;

    // phase A: layer 0 cell, weights in LDS
    {
      const float* vsrc = half ? (DH + (0*2 + par)*1024) : (dec_emb + (size_t)tok*1024);
      const float4* z4 = (const float4*)vsrc;
      float4 zv0 = z4[lane], zv1 = z4[64+lane], zv2 = z4[128+lane], zv3 = z4[192+lane];
      const float* wl = lds + pl*8192 + half*1024;
      float acc[4];
#pragma unroll
      for (int g = 0; g < 4; ++g) {
        const float4* w4 = (const float4*)(wl + g*2048);
        float4 w0 = w4[lane], w1 = w4[64+lane], w2 = w4[128+lane], w3 = w4[192+lane];
        acc[g] = w0.x*zv0.x+w0.y*zv0.y+w0.z*zv0.z+w0.w*zv0.w
               + w1.x*zv1.x+w1.y*zv1.y+w1.z*zv1.z+w1.w*zv1.w
               + w2.x*zv2.x+w2.y*zv2.y+w2.z*zv2.z+w2.w*zv2.w
               + w3.x*zv3.x+w3.y*zv3.y+w3.z*zv3.z+w3.w*zv3.w;
      }
#pragma unroll
      for (int g = 0; g < 4; ++g) acc[g] = wredsum(acc[g]);
      if (lane == 0) { sg[pl][half][0]=acc[0]; sg[pl][half][1]=acc[1]; sg[pl][half][2]=acc[2]; sg[pl][half][3]=acc[3]; }
      __syncthreads();
      if (tid < 4) {
        float gi = sg[tid][0][0]+sg[tid][1][0] + b0i;
        float gf = sg[tid][0][1]+sg[tid][1][1] + b0f;
        float gg = sg[tid][0][2]+sg[tid][1][2] + b0g;
        float go = sg[tid][0][3]+sg[tid][1][3] + b0o;
        float cn = sigm(gf)*c0reg + sigm(gi)*tanh_(gg);
        float hn = sigm(go)*tanh_(cn);
        c0reg = cn;
        DH[(0*2 + (par^1))*1024 + j2] = hn;
      }
    }
    GB();

    // phase B: layer 1 cell, streamed weights (float4, grouped loads)
    {
      const float* Wih1 = dec_Wih + (size_t)4096*1024;
      const float* Whh1 = dec_Whh + (size_t)4096*1024;
      const float* vsrc = half ? (DH + (1*2 + par)*1024) : (DH + (0*2 + (par^1))*1024);
      const float* wsrc = half ? Whh1 : Wih1;
      const int j = blk*4 + pl;
      const float4* z4 = (const float4*)vsrc;
      float4 zv0 = z4[lane], zv1 = z4[64+lane], zv2 = z4[128+lane], zv3 = z4[192+lane];
      float acc[4];
#pragma unroll
      for (int g = 0; g < 4; ++g) {
        const float4* w4 = (const float4*)(wsrc + (size_t)(g*1024 + j)*1024);
        float4 w0 = w4[lane], w1 = w4[64+lane], w2 = w4[128+lane], w3 = w4[192+lane];
        acc[g] = w0.x*zv0.x+w0.y*zv0.y+w0.z*zv0.z+w0.w*zv0.w
               + w1.x*zv1.x+w1.y*zv1.y+w1.z*zv1.z+w1.w*zv1.w
               + w2.x*zv2.x+w2.y*zv2.y+w2.z*zv2.z+w2.w*zv2.w
               + w3.x*zv3.x+w3.y*zv3.y+w3.z*zv3.z+w3.w*zv3.w;
      }
#pragma unroll
      for (int g = 0; g < 4; ++g) acc[g] = wredsum(acc[g]);
      if (lane == 0) { sg[pl][half][0]=acc[0]; sg[pl][half][1]=acc[1]; sg[pl][half][2]=acc[2]; sg[pl][half][3]=acc[3]; }
      __syncthreads();
      if (tid < 4) {
        float gi = sg[tid][0][0]+sg[tid][1][0] + b1i;
        float gf = sg[tid][0][1]+sg[tid][1][1] + b1f;
        float gg = sg[tid][0][2]+sg[tid][1][2] + b1g;
        float go = sg[tid][0][3]+sg[tid][1][3] + b1o;
        float cn = sigm(gf)*c1reg + sigm(gi)*tanh_(gg);
        float hn = sigm(go)*tanh_(cn);
        c1reg = cn;
        DH[(1*2 + (par^1))*1024 + j2] = hn;
      }
      if (blk == 0 && tid == 0)
        __hip_atomic_store(&slots[(t+1)&1], 0ull, __ATOMIC_RELAXED, __HIP_MEMORY_SCOPE_AGENT);
    }
    GB();

    // phase C: classifier matvec (float4, 4-row groups) + logits + argmax
    {
      const float* h2 = DH + (1*2 + (par^1))*1024;
      const float4* h4 = (const float4*)h2;
      float4 hv0 = h4[lane], hv1 = h4[64+lane], hv2 = h4[128+lane], hv3 = h4[192+lane];
      const int gw = blk*8 + wave;
      float bv = -INFINITY; int bix = 0;
#pragma unroll 1
      for (int ii = 0; ii < 4; ++ii) {
        float a4[4];
#pragma unroll
        for (int r = 0; r < 4; ++r) {
          const int row = gw + (ii*4 + r)*2048;
          a4[r] = 0.f;
          if (row < VV) {
            const float4* w4 = (const float4*)(clf_W + (size_t)row*1024);
            float4 w0 = w4[lane], w1 = w4[64+lane], w2 = w4[128+lane], w3 = w4[192+lane];
            a4[r] = w0.x*hv0.x+w0.y*hv0.y+w0.z*hv0.z+w0.w*hv0.w
                  + w1.x*hv1.x+w1.y*hv1.y+w1.z*hv1.z+w1.w*hv1.w
                  + w2.x*hv2.x+w2.y*hv2.y+w2.z*hv2.z+w2.w*hv2.w
                  + w3.x*hv3.x+w3.y*hv3.y+w3.z*hv3.z+w3.w*hv3.w;
          }
        }
#pragma unroll
        for (int r = 0; r < 4; ++r) {
          const int row = gw + (ii*4 + r)*2048;
          if (row < VV) {
            float a = wredsum(a4[r]) + clf_b[row];
            if (lane == 0) LG[(size_t)t*VV + row] = a;
            if (a > bv) { bv = a; bix = row; }
          }
        }
      }
      if (lane == 0) { cbv[wave] = bv; cbi[wave] = bix; }
      __syncthreads();
      if (tid == 0) {
        float v = cbv[0]; int ix = cbi[0];
#pragma unroll
        for (int w2 = 1; w2 < 8; ++w2) {
          float v2 = cbv[w2]; int i2 = cbi[w2];
          if (v2 > v || (v2 == v && i2 < ix)) { v = v2; ix = i2; }
        }
        atomicMax(&slots[t&1], packmax(v, ix));
      }
    }
    GB();
  }
#undef GB
}

// final: softmax rows of LG[T][V], write transposed out[v*T + t]
__global__ __launch_bounds__(256, 1) void softmax_k(const float* __restrict__ LG, float* __restrict__ out){
  const int t = blockIdx.x, tid = threadIdx.x;
  __shared__ float red[256];
  const float* row = LG + (size_t)t*VV;
  float mx = -INFINITY;
  for (int v = tid; v < VV; v += 256) mx = fmaxf(mx, row[v]);
  red[tid] = mx; __syncthreads();
  for (int s = 128; s > 0; s >>= 1) { if (tid < s) red[tid] = fmaxf(red[tid], red[tid+s]); __syncthreads(); }
  mx = red[0]; __syncthreads();
  float sum = 0.f;
  for (int v = tid; v < VV; v += 256) sum += __expf(row[v]-mx);
  red[tid] = sum; __syncthreads();
  for (int s = 128; s > 0; s >>= 1) { if (tid < s) red[tid] += red[tid+s]; __syncthreads(); }
  float inv = 1.f/red[0];
  for (int v = tid; v < VV; v += 256) out[(size_t)v*TT + t] = __expf(row[v]-mx)*inv;
}

extern "C" void kernel_launch(void* const* d_in, const int* in_sizes, int n_in,
                              void* d_out, int out_size, void* d_ws, size_t ws_size,
                              hipStream_t stream) {
  const int*   x       = (const int*)d_in[0];
  const float* enc_emb = (const float*)d_in[1];
  const float* enc_Wih = (const float*)d_in[2];
  const float* enc_Whh = (const float*)d_in[3];
  const float* enc_b   = (const float*)d_in[4];
  const float* dec_emb = (const float*)d_in[5];
  const float* dec_Wih = (const float*)d_in[6];
  const float* dec_Whh = (const float*)d_in[7];
  const float* dec_b   = (const float*)d_in[8];
  const float* clf_W   = (const float*)d_in[9];
  const float* clf_b   = (const float*)d_in[10];
  float* ws = (float*)d_ws;

  hipMemsetAsync(d_ws, 0, CTRL_BYTES, stream);  // gen + slots + flags
  hipLaunchKernelGGL(seq2seq_k, dim3(NB), dim3(BT), 0, stream,
                     x, enc_emb, enc_Wih, enc_Whh, enc_b,
                     dec_emb, dec_Wih, dec_Whh, dec_b, clf_W, clf_b, ws);
  hipLaunchKernelGGL(softmax_k, dim3(TT), dim3(256), 0, stream,
                     ws + OF_LOG, (float*)d_out);
}